// Round 1
// baseline (452.043 us; speedup 1.0000x reference)
//
#include <hip/hip_runtime.h>

typedef int v4i __attribute__((ext_vector_type(4)));

#define EPS_F 1e-8f

#define GLOAD_LDS16(g, l)                                              \
    __builtin_amdgcn_global_load_lds(                                  \
        (const __attribute__((address_space(1))) void*)(g),            \
        (__attribute__((address_space(3))) void*)(l), 16, 0, 0)

// ---------------- kernel 1: sum |w| in fp64 ----------------
__global__ void __launch_bounds__(256) wabs_sum_kernel(const float* __restrict__ w,
                                                       double* __restrict__ out, int n4) {
    const float4* w4 = (const float4*)w;
    double s = 0.0;
    int idx = blockIdx.x * 256 + threadIdx.x;
    int stride = gridDim.x * 256;
    for (int i = idx; i < n4; i += stride) {
        float4 v = w4[i];
        s += (double)fabsf(v.x) + (double)fabsf(v.y) +
             (double)fabsf(v.z) + (double)fabsf(v.w);
    }
    for (int off = 32; off > 0; off >>= 1)
        s += __shfl_down(s, off);
    __shared__ double sm[4];
    if ((threadIdx.x & 63) == 0) sm[threadIdx.x >> 6] = s;
    __syncthreads();
    if (threadIdx.x == 0) {
        atomicAdd(out, sm[0] + sm[1] + sm[2] + sm[3]);
    }
}

// ---------------- kernel 2: ternary-quantize W -> int8 ----------------
__global__ void __launch_bounds__(256) wquant_kernel(const float* __restrict__ w,
                                                     const double* __restrict__ wsum,
                                                     signed char* __restrict__ wq,
                                                     int n4, int n) {
    float wsf = (float)(wsum[0] / (double)n) + EPS_F;
    const float4* w4 = (const float4*)w;
    unsigned int* q4 = (unsigned int*)wq;
    int idx = blockIdx.x * 256 + threadIdx.x;
    int stride = gridDim.x * 256;
    for (int i = idx; i < n4; i += stride) {
        float4 v = w4[i];
        int q0 = min(1, max(-1, (int)rintf(v.x / wsf)));
        int q1 = min(1, max(-1, (int)rintf(v.y / wsf)));
        int q2 = min(1, max(-1, (int)rintf(v.z / wsf)));
        int q3 = min(1, max(-1, (int)rintf(v.w / wsf)));
        q4[i] = (q0 & 0xff) | ((q1 & 0xff) << 8) | ((q2 & 0xff) << 16) | ((q3 & 0xff) << 24);
    }
}

// ---------------- kernel 3: per-token int8 activation quant ----------------
// one block (256 threads) per row of K=4096
__global__ void __launch_bounds__(256) xquant_kernel(const float* __restrict__ x,
                                                     signed char* __restrict__ xq,
                                                     float* __restrict__ xscale, int K) {
    int row = blockIdx.x;
    const float4* xr = (const float4*)(x + (size_t)row * K);
    unsigned int* qr = (unsigned int*)(xq + (size_t)row * K);
    int t = threadIdx.x;
    float4 v[4];
    float mx = 0.0f;
#pragma unroll
    for (int j = 0; j < 4; j++) {
        v[j] = xr[t + j * 256];
        mx = fmaxf(mx, fmaxf(fmaxf(fabsf(v[j].x), fabsf(v[j].y)),
                             fmaxf(fabsf(v[j].z), fabsf(v[j].w))));
    }
    for (int off = 32; off > 0; off >>= 1)
        mx = fmaxf(mx, __shfl_down(mx, off));
    __shared__ float sm[4];
    if ((t & 63) == 0) sm[t >> 6] = mx;
    __syncthreads();
    float scale = fmaxf(fmaxf(fmaxf(sm[0], sm[1]), fmaxf(sm[2], sm[3])), EPS_F);
    float inv = 127.0f / scale;
#pragma unroll
    for (int j = 0; j < 4; j++) {
        int q0 = min(127, max(-127, (int)rintf(v[j].x * inv)));
        int q1 = min(127, max(-127, (int)rintf(v[j].y * inv)));
        int q2 = min(127, max(-127, (int)rintf(v[j].z * inv)));
        int q3 = min(127, max(-127, (int)rintf(v[j].w * inv)));
        qr[t + j * 256] = (q0 & 0xff) | ((q1 & 0xff) << 8) | ((q2 & 0xff) << 16) | ((q3 & 0xff) << 24);
    }
    if (t == 0) xscale[row] = scale;
}

// ---------------- kernel 4: int8 MFMA GEMM + dequant epilogue ----------------
// C[m,n] = sum_k Aq[m,k]*Bq[n,k]  (both row-major along K), then scale.
// 128x128 tile, BK=64, 4 waves (2x2), each wave 64x64 via 4x4 of 16x16x64 MFMA.
__global__ void __launch_bounds__(256) gemm_i8_kernel(const signed char* __restrict__ Aq,
                                                      const signed char* __restrict__ Bq,
                                                      const float* __restrict__ xscale,
                                                      const double* __restrict__ wsum,
                                                      float* __restrict__ C,
                                                      int M, int N, int K, int wcount) {
    constexpr int BM = 128, BN = 128, BK = 64;
    __shared__ signed char As[BM * BK];
    __shared__ signed char Bs[BN * BK];

    const int tid = threadIdx.x;
    const int wave = tid >> 6;
    const int lane = tid & 63;
    const int quad = lane >> 4;
    const int l16 = lane & 15;
    const int waveM = (wave & 1) * 64;
    const int waveN = (wave >> 1) * 64;
    const int bm = blockIdx.y * BM;
    const int bn = blockIdx.x * BN;

    v4i acc[4][4];
    const v4i vzero = {0, 0, 0, 0};
#pragma unroll
    for (int i = 0; i < 4; i++)
#pragma unroll
        for (int j = 0; j < 4; j++) acc[i][j] = vzero;

    // staging: 512 segments of 16B per operand; thread handles s0 and s0+256
    const int s0 = wave * 64 + lane;   // 0..255
    const int s1 = s0 + 256;           // 256..511
    const signed char* agp0 = Aq + (size_t)(bm + (s0 >> 2)) * K + ((s0 & 3) * 16);
    const signed char* agp1 = Aq + (size_t)(bm + (s1 >> 2)) * K + ((s1 & 3) * 16);
    const signed char* bgp0 = Bq + (size_t)(bn + (s0 >> 2)) * K + ((s0 & 3) * 16);
    const signed char* bgp1 = Bq + (size_t)(bn + (s1 >> 2)) * K + ((s1 & 3) * 16);
    signed char* alp0 = As + s0 * 16;
    signed char* alp1 = As + s1 * 16;
    signed char* blp0 = Bs + s0 * 16;
    signed char* blp1 = Bs + s1 * 16;

    const v4i* As4 = (const v4i*)As;
    const v4i* Bs4 = (const v4i*)Bs;
    const int arow = waveM + l16;
    const int brow = waveN + l16;

    for (int k0 = 0; k0 < K; k0 += BK) {
        GLOAD_LDS16(agp0 + k0, alp0);
        GLOAD_LDS16(agp1 + k0, alp1);
        GLOAD_LDS16(bgp0 + k0, blp0);
        GLOAD_LDS16(bgp1 + k0, blp1);
        __syncthreads();

        v4i af[4], bf[4];
#pragma unroll
        for (int mt = 0; mt < 4; mt++) af[mt] = As4[(arow + mt * 16) * 4 + quad];
#pragma unroll
        for (int nt = 0; nt < 4; nt++) bf[nt] = Bs4[(brow + nt * 16) * 4 + quad];
#pragma unroll
        for (int mt = 0; mt < 4; mt++)
#pragma unroll
            for (int nt = 0; nt < 4; nt++)
                acc[mt][nt] = __builtin_amdgcn_mfma_i32_16x16x64_i8(af[mt], bf[nt], acc[mt][nt], 0, 0, 0);
        __syncthreads();
    }

    // epilogue: C/D layout col = lane&15 (N), row = quad*4+reg (M)
    float wsf = (float)(wsum[0] / (double)wcount) + EPS_F;
    const float wk = wsf / 127.0f;
#pragma unroll
    for (int mt = 0; mt < 4; mt++) {
        int gm0 = bm + waveM + mt * 16 + quad * 4;
#pragma unroll
        for (int reg = 0; reg < 4; reg++) {
            int gm = gm0 + reg;
            float s = xscale[gm] * wk;
            float* crow = C + (size_t)gm * N + bn + waveN + l16;
#pragma unroll
            for (int nt = 0; nt < 4; nt++)
                crow[nt * 16] = (float)acc[mt][nt][reg] * s;
        }
    }
}

extern "C" void kernel_launch(void* const* d_in, const int* in_sizes, int n_in,
                              void* d_out, int out_size, void* d_ws, size_t ws_size,
                              hipStream_t stream) {
    const float* x = (const float*)d_in[0];
    const float* w = (const float*)d_in[1];
    float* y = (float*)d_out;

    const int K = 4096, N = 4096;
    const int M = in_sizes[0] / K;       // 8192
    const int wcount = in_sizes[1];      // N*K

    double* wsum = (double*)d_ws;
    float* xscale = (float*)((char*)d_ws + 256);
    signed char* xq = (signed char*)((char*)d_ws + 256 + 65536);
    signed char* wq = xq + (size_t)M * K;

    hipMemsetAsync(wsum, 0, sizeof(double), stream);
    wabs_sum_kernel<<<1024, 256, 0, stream>>>(w, wsum, wcount / 4);
    wquant_kernel<<<1024, 256, 0, stream>>>(w, wsum, wq, wcount / 4, wcount);
    xquant_kernel<<<M, 256, 0, stream>>>(x, xq, xscale, K);
    dim3 grid(N / 128, M / 128);
    gemm_i8_kernel<<<grid, 256, 0, stream>>>(xq, wq, xscale, wsum, y, M, N, K, wcount);
}

// Round 2
// 449.903 us; speedup vs baseline: 1.0048x; 1.0048x over previous
//
#include <hip/hip_runtime.h>

typedef int v4i __attribute__((ext_vector_type(4)));
typedef int v16i __attribute__((ext_vector_type(16)));

#define EPS_F 1e-8f

#define GLOAD_LDS16(g, l)                                              \
    __builtin_amdgcn_global_load_lds(                                  \
        (const __attribute__((address_space(1))) void*)(g),            \
        (__attribute__((address_space(3))) void*)(l), 16, 0, 0)

// ---------------- kernel 1: sum |w| in fp64 ----------------
__global__ void __launch_bounds__(256) wabs_sum_kernel(const float* __restrict__ w,
                                                       double* __restrict__ out, int n4) {
    const float4* w4 = (const float4*)w;
    double s = 0.0;
    int idx = blockIdx.x * 256 + threadIdx.x;
    int stride = gridDim.x * 256;
    for (int i = idx; i < n4; i += stride) {
        float4 v = w4[i];
        s += (double)fabsf(v.x) + (double)fabsf(v.y) +
             (double)fabsf(v.z) + (double)fabsf(v.w);
    }
    for (int off = 32; off > 0; off >>= 1)
        s += __shfl_down(s, off);
    __shared__ double sm[4];
    if ((threadIdx.x & 63) == 0) sm[threadIdx.x >> 6] = s;
    __syncthreads();
    if (threadIdx.x == 0) {
        atomicAdd(out, sm[0] + sm[1] + sm[2] + sm[3]);
    }
}

// ---------------- kernel 2: ternary-quantize W -> int8 (reciprocal, no div) ----------------
__global__ void __launch_bounds__(256) wquant_kernel(const float* __restrict__ w,
                                                     const double* __restrict__ wsum,
                                                     signed char* __restrict__ wq,
                                                     int n4, int n) {
    float wsf = (float)(wsum[0] / (double)n) + EPS_F;
    float inv = 1.0f / wsf;   // one uniform divide; per-element mul below
    const float4* w4 = (const float4*)w;
    unsigned int* q4 = (unsigned int*)wq;
    int idx = blockIdx.x * 256 + threadIdx.x;
    int stride = gridDim.x * 256;
    for (int i = idx; i < n4; i += stride) {
        float4 v = w4[i];
        int q0 = min(1, max(-1, (int)rintf(v.x * inv)));
        int q1 = min(1, max(-1, (int)rintf(v.y * inv)));
        int q2 = min(1, max(-1, (int)rintf(v.z * inv)));
        int q3 = min(1, max(-1, (int)rintf(v.w * inv)));
        q4[i] = (q0 & 0xff) | ((q1 & 0xff) << 8) | ((q2 & 0xff) << 16) | ((q3 & 0xff) << 24);
    }
}

// ---------------- kernel 3: per-token int8 activation quant ----------------
__global__ void __launch_bounds__(256) xquant_kernel(const float* __restrict__ x,
                                                     signed char* __restrict__ xq,
                                                     float* __restrict__ xscale, int K) {
    int row = blockIdx.x;
    const float4* xr = (const float4*)(x + (size_t)row * K);
    unsigned int* qr = (unsigned int*)(xq + (size_t)row * K);
    int t = threadIdx.x;
    float4 v[4];
    float mx = 0.0f;
#pragma unroll
    for (int j = 0; j < 4; j++) {
        v[j] = xr[t + j * 256];
        mx = fmaxf(mx, fmaxf(fmaxf(fabsf(v[j].x), fabsf(v[j].y)),
                             fmaxf(fabsf(v[j].z), fabsf(v[j].w))));
    }
    for (int off = 32; off > 0; off >>= 1)
        mx = fmaxf(mx, __shfl_down(mx, off));
    __shared__ float sm[4];
    if ((t & 63) == 0) sm[t >> 6] = mx;
    __syncthreads();
    float scale = fmaxf(fmaxf(fmaxf(sm[0], sm[1]), fmaxf(sm[2], sm[3])), EPS_F);
    float inv = 127.0f / scale;
#pragma unroll
    for (int j = 0; j < 4; j++) {
        int q0 = min(127, max(-127, (int)rintf(v[j].x * inv)));
        int q1 = min(127, max(-127, (int)rintf(v[j].y * inv)));
        int q2 = min(127, max(-127, (int)rintf(v[j].z * inv)));
        int q3 = min(127, max(-127, (int)rintf(v[j].w * inv)));
        qr[t + j * 256] = (q0 & 0xff) | ((q1 & 0xff) << 8) | ((q2 & 0xff) << 16) | ((q3 & 0xff) << 24);
    }
    if (t == 0) xscale[row] = scale;
}

// ---------------- kernel 4: int8 MFMA GEMM (32x32x32), swizzled LDS ----------------
// Block tile 256(M) x 128(N), BK=64. 4 waves 2x2; wave tile 128x64 = 4x2 of 32x32.
// LDS: As 256x64B = 16KB, Bs 128x64B = 8KB. 16B chunk index XOR-swizzled by row&3
// at staging time (permute GLOBAL source; LDS side of global_load_lds is fixed
// lane order). Reads then alias at most 2-way (free per m136).
__global__ void __launch_bounds__(256, 2) gemm_i8_kernel(const signed char* __restrict__ Aq,
                                                         const signed char* __restrict__ Bq,
                                                         const float* __restrict__ xscale,
                                                         const double* __restrict__ wsum,
                                                         float* __restrict__ C,
                                                         int M, int N, int K, int wcount) {
    constexpr int BM = 256, BN = 128, BK = 64;
    __shared__ signed char As[BM * BK];
    __shared__ signed char Bs[BN * BK];

    const int tid = threadIdx.x;
    const int wave = tid >> 6;
    const int lane = tid & 63;
    const int l32 = lane & 31;
    const int half = lane >> 5;
    const int waveM = (wave & 1) * 128;
    const int waveN = (wave >> 1) * 64;
    const int bm = blockIdx.y * BM;
    const int bn = blockIdx.x * BN;

    v16i acc[4][2];
#pragma unroll
    for (int mt = 0; mt < 4; mt++)
#pragma unroll
        for (int nt = 0; nt < 2; nt++)
#pragma unroll
            for (int r = 0; r < 16; r++) acc[mt][nt][r] = 0;

    // staging: As has 1024 16B segments, Bs has 512. Thread t owns segments
    // t+j*256. Segment s holds (row=s>>2, chunk=(s&3)^(row&3)) of the tile.
    const signed char* asrc[4];
    signed char* adst[4];
#pragma unroll
    for (int j = 0; j < 4; j++) {
        int s = tid + j * 256;
        int r = s >> 2;
        int c = (s & 3) ^ (r & 3);
        asrc[j] = Aq + (size_t)(bm + r) * K + c * 16;
        adst[j] = As + s * 16;
    }
    const signed char* bsrc[2];
    signed char* bdst[2];
#pragma unroll
    for (int j = 0; j < 2; j++) {
        int s = tid + j * 256;
        int r = s >> 2;
        int c = (s & 3) ^ (r & 3);
        bsrc[j] = Bq + (size_t)(bn + r) * K + c * 16;
        bdst[j] = Bs + s * 16;
    }

    const v4i* As4 = (const v4i*)As;
    const v4i* Bs4 = (const v4i*)Bs;

    for (int k0 = 0; k0 < K; k0 += BK) {
#pragma unroll
        for (int j = 0; j < 4; j++) GLOAD_LDS16(asrc[j] + k0, adst[j]);
#pragma unroll
        for (int j = 0; j < 2; j++) GLOAD_LDS16(bsrc[j] + k0, bdst[j]);
        __syncthreads();

#pragma unroll
        for (int ks = 0; ks < 2; ks++) {
            const int q = ks * 2 + half;          // 16B chunk index within row
            const int swz = q ^ (l32 & 3);        // rows are +32-aligned per tile
            v4i af[4], bf[2];
#pragma unroll
            for (int mt = 0; mt < 4; mt++) {
                int row = waveM + mt * 32 + l32;
                af[mt] = As4[row * 4 + swz];
            }
#pragma unroll
            for (int nt = 0; nt < 2; nt++) {
                int row = waveN + nt * 32 + l32;
                bf[nt] = Bs4[row * 4 + swz];
            }
#pragma unroll
            for (int mt = 0; mt < 4; mt++)
#pragma unroll
                for (int nt = 0; nt < 2; nt++)
                    acc[mt][nt] = __builtin_amdgcn_mfma_i32_32x32x32_i8(af[mt], bf[nt],
                                                                        acc[mt][nt], 0, 0, 0);
        }
        __syncthreads();
    }

    // epilogue: 32x32 C/D layout: col = lane&31, row = (r&3) + 8*(r>>2) + 4*half
    float wsf = (float)(wsum[0] / (double)wcount) + EPS_F;
    const float wk = wsf / 127.0f;
#pragma unroll
    for (int mt = 0; mt < 4; mt++) {
        int rowbase = bm + waveM + mt * 32 + 4 * half;
#pragma unroll
        for (int r = 0; r < 16; r++) {
            int gm = rowbase + (r & 3) + 8 * (r >> 2);
            float s = xscale[gm] * wk;
            float* crow = C + (size_t)gm * N + bn + waveN + l32;
            crow[0]  = (float)acc[mt][0][r] * s;
            crow[32] = (float)acc[mt][1][r] * s;
        }
    }
}

extern "C" void kernel_launch(void* const* d_in, const int* in_sizes, int n_in,
                              void* d_out, int out_size, void* d_ws, size_t ws_size,
                              hipStream_t stream) {
    const float* x = (const float*)d_in[0];
    const float* w = (const float*)d_in[1];
    float* y = (float*)d_out;

    const int K = 4096, N = 4096;
    const int M = in_sizes[0] / K;       // 8192
    const int wcount = in_sizes[1];      // N*K

    double* wsum = (double*)d_ws;
    float* xscale = (float*)((char*)d_ws + 256);
    signed char* xq = (signed char*)((char*)d_ws + 256 + 65536);
    signed char* wq = xq + (size_t)M * K;

    hipMemsetAsync(wsum, 0, sizeof(double), stream);
    wabs_sum_kernel<<<1024, 256, 0, stream>>>(w, wsum, wcount / 4);
    wquant_kernel<<<1024, 256, 0, stream>>>(w, wsum, wq, wcount / 4, wcount);
    xquant_kernel<<<M, 256, 0, stream>>>(x, xq, xscale, K);
    dim3 grid(N / 128, M / 256);
    gemm_i8_kernel<<<grid, 256, 0, stream>>>(xq, wq, xscale, wsum, y, M, N, K, wcount);
}